// Round 1
// baseline (1014.741 us; speedup 1.0000x reference)
//
#include <hip/hip_runtime.h>
#include <math.h>

#define N_NODES 100000
#define N_EDGES 1600000
#define IN_FEAT 128
#define HIDDEN 64
#define N_CLASSES 16

// ---------------- degree / normalization ----------------

__global__ void deg_init_k(float* __restrict__ deg) {
    int i = blockIdx.x * blockDim.x + threadIdx.x;
    if (i < N_NODES) deg[i] = 1.0f;  // self-loop
}

__global__ void deg_count_k(const int* __restrict__ dst, float* __restrict__ deg) {
    int e = blockIdx.x * blockDim.x + threadIdx.x;
    if (e < N_EDGES) atomicAdd(&deg[dst[e]], 1.0f);
}

__global__ void dinv_k(float* __restrict__ deg) {
    int i = blockIdx.x * blockDim.x + threadIdx.x;
    if (i < N_NODES) {
        float d = deg[i];
        deg[i] = (d > 0.0f) ? (1.0f / sqrtf(d)) : 0.0f;
    }
}

// ---------------- GEMM 1: hw = x @ W1   [N,128]x[128,64] ----------------
// block = 256 threads = 4 rows x 64 cols. W1 (32KB) staged in LDS.

__global__ __launch_bounds__(256) void gemm1_k(const float* __restrict__ x,
                                               const float* __restrict__ W,
                                               float* __restrict__ hw) {
    __shared__ float Ws[IN_FEAT * HIDDEN];  // 32 KB
    __shared__ float xs[4][IN_FEAT];        // 2 KB
    int tid = threadIdx.x;

    const float4* W4 = (const float4*)W;
    float4* Ws4 = (float4*)Ws;
    #pragma unroll
    for (int i = 0; i < (IN_FEAT * HIDDEN / 4) / 256; ++i)
        Ws4[tid + i * 256] = W4[tid + i * 256];

    int row0 = blockIdx.x * 4;
    const float4* x4 = (const float4*)(x + (size_t)row0 * IN_FEAT);
    float4* xs4 = (float4*)xs;
    if (tid < 4 * IN_FEAT / 4) xs4[tid] = x4[tid];
    __syncthreads();

    int col = tid & 63;
    int r = tid >> 6;
    float acc = 0.0f;
    #pragma unroll 16
    for (int k = 0; k < IN_FEAT; ++k)
        acc += xs[r][k] * Ws[k * HIDDEN + col];
    hw[(size_t)(row0 + r) * HIDDEN + col] = acc;
}

// ---------------- GEMM 2: hw = relu(agg) @ W2   [N,64]x[64,64] ----------------

__global__ __launch_bounds__(256) void gemm2_k(const float* __restrict__ agg,
                                               const float* __restrict__ W,
                                               float* __restrict__ hw) {
    __shared__ float Ws[HIDDEN * HIDDEN];  // 16 KB
    __shared__ float xs[4][HIDDEN];
    int tid = threadIdx.x;

    const float4* W4 = (const float4*)W;
    float4* Ws4 = (float4*)Ws;
    #pragma unroll
    for (int i = 0; i < (HIDDEN * HIDDEN / 4) / 256; ++i)
        Ws4[tid + i * 256] = W4[tid + i * 256];

    int row0 = blockIdx.x * 4;
    const float4* a4 = (const float4*)(agg + (size_t)row0 * HIDDEN);
    float4* xs4 = (float4*)xs;
    if (tid < 4 * HIDDEN / 4) {
        float4 v = a4[tid];
        v.x = fmaxf(v.x, 0.f); v.y = fmaxf(v.y, 0.f);
        v.z = fmaxf(v.z, 0.f); v.w = fmaxf(v.w, 0.f);
        xs4[tid] = v;
    }
    __syncthreads();

    int col = tid & 63;
    int r = tid >> 6;
    float acc = 0.0f;
    #pragma unroll
    for (int k = 0; k < HIDDEN; ++k)
        acc += xs[r][k] * Ws[k * HIDDEN + col];
    hw[(size_t)(row0 + r) * HIDDEN + col] = acc;
}

// ---------------- agg init: agg = b + hw * dinv^2 (self-loop + bias) ----------------

__global__ void init_agg_k(const float* __restrict__ hw, const float* __restrict__ dinv,
                           const float* __restrict__ b, float* __restrict__ agg) {
    int i = blockIdx.x * blockDim.x + threadIdx.x;  // over N*64
    if (i < N_NODES * HIDDEN) {
        int node = i >> 6;
        int c = i & 63;
        float di = dinv[node];
        agg[i] = b[c] + hw[i] * di * di;
    }
}

// ---------------- edge scatter: agg[dst] += hw[src] * dinv[src]*dinv[dst] ----------------
// one wave (64 lanes) per edge; lane = feature channel

__global__ __launch_bounds__(256) void scatter_k(const int* __restrict__ src,
                                                 const int* __restrict__ dst,
                                                 const float* __restrict__ dinv,
                                                 const float* __restrict__ hw,
                                                 float* __restrict__ agg) {
    int e = (blockIdx.x * 256 + threadIdx.x) >> 6;
    int lane = threadIdx.x & 63;
    if (e < N_EDGES) {
        int s = src[e];
        int d = dst[e];
        float nrm = dinv[s] * dinv[d];
        float v = hw[(size_t)s * HIDDEN + lane] * nrm;
        atomicAdd(&agg[(size_t)d * HIDDEN + lane], v);
    }
}

// ---------------- final: out = relu(agg) @ Wl + bl   [N,64]x[64,16] ----------------
// block = 256 = 16 rows x 16 cols

__global__ __launch_bounds__(256) void final_k(const float* __restrict__ agg,
                                               const float* __restrict__ Wl,
                                               const float* __restrict__ bl,
                                               float* __restrict__ out) {
    __shared__ float Ws[HIDDEN * N_CLASSES];  // 4 KB
    __shared__ float hs[16][HIDDEN + 1];      // padded: stride 65 breaks bank aliasing
    int tid = threadIdx.x;

    if (tid < HIDDEN * N_CLASSES / 4) ((float4*)Ws)[tid] = ((const float4*)Wl)[tid];

    int row0 = blockIdx.x * 16;
    for (int i = tid; i < 16 * HIDDEN; i += 256) {
        int rr = i >> 6;
        int kk = i & 63;
        hs[rr][kk] = fmaxf(agg[(size_t)(row0 + rr) * HIDDEN + kk], 0.0f);
    }
    __syncthreads();

    int col = tid & 15;
    int r = tid >> 4;
    float acc = bl[col];
    #pragma unroll
    for (int k = 0; k < HIDDEN; ++k)
        acc += hs[r][k] * Ws[k * N_CLASSES + col];
    out[(size_t)(row0 + r) * N_CLASSES + col] = acc;
}

// ---------------- launch ----------------

extern "C" void kernel_launch(void* const* d_in, const int* in_sizes, int n_in,
                              void* d_out, int out_size, void* d_ws, size_t ws_size,
                              hipStream_t stream) {
    const float* x  = (const float*)d_in[0];
    const int*   ei = (const int*)d_in[1];   // [2, E] int32
    const float* W1 = (const float*)d_in[2];
    const float* b1 = (const float*)d_in[3];
    const float* W2 = (const float*)d_in[4];
    const float* b2 = (const float*)d_in[5];
    const float* Wl = (const float*)d_in[6];
    const float* bl = (const float*)d_in[7];
    float* out = (float*)d_out;

    const int* src = ei;
    const int* dst = ei + N_EDGES;

    // workspace layout: deg/dinv [N], hw [N*64], agg [N*64]  => ~51.6 MB
    float* deg = (float*)d_ws;
    float* hw  = deg + N_NODES;
    float* agg = hw + (size_t)N_NODES * HIDDEN;

    // normalization
    deg_init_k<<<(N_NODES + 255) / 256, 256, 0, stream>>>(deg);
    deg_count_k<<<(N_EDGES + 255) / 256, 256, 0, stream>>>(dst, deg);
    dinv_k<<<(N_NODES + 255) / 256, 256, 0, stream>>>(deg);  // deg buffer now holds dinv

    // layer 1
    gemm1_k<<<N_NODES / 4, 256, 0, stream>>>(x, W1, hw);
    init_agg_k<<<N_NODES * HIDDEN / 256, 256, 0, stream>>>(hw, deg, b1, agg);
    scatter_k<<<N_EDGES / 4, 256, 0, stream>>>(src, dst, deg, hw, agg);

    // layer 2 (relu fused into gemm2 load)
    gemm2_k<<<N_NODES / 4, 256, 0, stream>>>(agg, W2, hw);
    init_agg_k<<<N_NODES * HIDDEN / 256, 256, 0, stream>>>(hw, deg, b2, agg);
    scatter_k<<<N_EDGES / 4, 256, 0, stream>>>(src, dst, deg, hw, agg);

    // classifier head (relu fused into load)
    final_k<<<N_NODES / 16, 256, 0, stream>>>(agg, Wl, bl, out);
}

// Round 2
// 574.870 us; speedup vs baseline: 1.7652x; 1.7652x over previous
//
#include <hip/hip_runtime.h>
#include <math.h>

#define N_NODES 100000
#define N_EDGES 1600000
#define IN_FEAT 128
#define HIDDEN 64
#define N_CLASSES 16

#define CHUNK 512
#define NB ((N_NODES + CHUNK - 1) / CHUNK)  // 196

// ---------------- degree / CSR build ----------------

__global__ void zero_deg_k(int* __restrict__ deg) {
    int i = blockIdx.x * blockDim.x + threadIdx.x;
    if (i < N_NODES) deg[i] = 0;
}

__global__ void hist_k(const int* __restrict__ dst, int* __restrict__ deg) {
    int e = blockIdx.x * blockDim.x + threadIdx.x;
    if (e < N_EDGES) atomicAdd(&deg[dst[e]], 1);
}

__global__ void dinv_k(const int* __restrict__ deg, float* __restrict__ dinv) {
    int i = blockIdx.x * blockDim.x + threadIdx.x;
    if (i < N_NODES) dinv[i] = 1.0f / sqrtf((float)(deg[i] + 1));  // +1 self-loop
}

__global__ __launch_bounds__(256) void chunk_sum_k(const int* __restrict__ deg,
                                                   int* __restrict__ blk_sum) {
    __shared__ int sm[256];
    int b = blockIdx.x, t = threadIdx.x;
    int i0 = b * CHUNK + t;
    int v = 0;
    if (i0 < N_NODES) v += deg[i0];
    if (i0 + 256 < N_NODES) v += deg[i0 + 256];
    sm[t] = v;
    __syncthreads();
    for (int s = 128; s > 0; s >>= 1) {
        if (t < s) sm[t] += sm[t + s];
        __syncthreads();
    }
    if (t == 0) blk_sum[b] = sm[0];
}

__global__ __launch_bounds__(256) void scan_blocks_k(const int* __restrict__ blk_sum,
                                                     int* __restrict__ blk_off,
                                                     int* __restrict__ row_ptr) {
    __shared__ int sm[256];
    int t = threadIdx.x;
    int v = (t < NB) ? blk_sum[t] : 0;
    sm[t] = v;
    __syncthreads();
    for (int s = 1; s < 256; s <<= 1) {
        int add = (t >= s) ? sm[t - s] : 0;
        __syncthreads();
        sm[t] += add;
        __syncthreads();
    }
    if (t < NB) blk_off[t] = sm[t] - v;  // exclusive
    if (t == 0) row_ptr[N_NODES] = N_EDGES;
}

__global__ __launch_bounds__(256) void rowptr_k(const int* __restrict__ deg,
                                                const int* __restrict__ blk_off,
                                                int* __restrict__ row_ptr,
                                                int* __restrict__ cursor) {
    __shared__ int pair[256];
    int b = blockIdx.x, t = threadIdx.x;
    int i0 = b * CHUNK + 2 * t;
    int d0 = (i0 < N_NODES) ? deg[i0] : 0;
    int d1 = (i0 + 1 < N_NODES) ? deg[i0 + 1] : 0;
    int p = d0 + d1;
    pair[t] = p;
    __syncthreads();
    for (int s = 1; s < 256; s <<= 1) {
        int add = (t >= s) ? pair[t - s] : 0;
        __syncthreads();
        pair[t] += add;
        __syncthreads();
    }
    int excl = pair[t] - p + blk_off[b];
    if (i0 < N_NODES)     { row_ptr[i0]     = excl;      cursor[i0]     = excl; }
    if (i0 + 1 < N_NODES) { row_ptr[i0 + 1] = excl + d0; cursor[i0 + 1] = excl + d0; }
}

__global__ void fill_k(const int* __restrict__ src, const int* __restrict__ dst,
                       int* __restrict__ cursor, int* __restrict__ csr_src) {
    int e = blockIdx.x * blockDim.x + threadIdx.x;
    if (e < N_EDGES) {
        int pos = atomicAdd(&cursor[dst[e]], 1);
        csr_src[pos] = src[e];
    }
}

// ---------------- GEMM 1: hws = (x @ W1) * dinv[row]   [N,128]x[128,64] ----------------

__global__ __launch_bounds__(256) void gemm1_k(const float* __restrict__ x,
                                               const float* __restrict__ W,
                                               const float* __restrict__ dinv,
                                               float* __restrict__ hws) {
    __shared__ float Ws[IN_FEAT * HIDDEN];  // 32 KB
    __shared__ float xs[4][IN_FEAT];
    int tid = threadIdx.x;

    const float4* W4 = (const float4*)W;
    float4* Ws4 = (float4*)Ws;
    #pragma unroll
    for (int i = 0; i < (IN_FEAT * HIDDEN / 4) / 256; ++i)
        Ws4[tid + i * 256] = W4[tid + i * 256];

    int row0 = blockIdx.x * 4;
    const float4* x4 = (const float4*)(x + (size_t)row0 * IN_FEAT);
    float4* xs4 = (float4*)xs;
    if (tid < 4 * IN_FEAT / 4) xs4[tid] = x4[tid];
    __syncthreads();

    int col = tid & 63;
    int r = tid >> 6;
    float acc = 0.0f;
    #pragma unroll 16
    for (int k = 0; k < IN_FEAT; ++k)
        acc += xs[r][k] * Ws[k * HIDDEN + col];
    hws[(size_t)(row0 + r) * HIDDEN + col] = acc * dinv[row0 + r];
}

// ---------------- GEMM 2: hws = (relu(agg) @ W2) * dinv[row] ----------------

__global__ __launch_bounds__(256) void gemm2_k(const float* __restrict__ agg,
                                               const float* __restrict__ W,
                                               const float* __restrict__ dinv,
                                               float* __restrict__ hws) {
    __shared__ float Ws[HIDDEN * HIDDEN];  // 16 KB
    __shared__ float xs[4][HIDDEN];
    int tid = threadIdx.x;

    const float4* W4 = (const float4*)W;
    float4* Ws4 = (float4*)Ws;
    #pragma unroll
    for (int i = 0; i < (HIDDEN * HIDDEN / 4) / 256; ++i)
        Ws4[tid + i * 256] = W4[tid + i * 256];

    int row0 = blockIdx.x * 4;
    const float4* a4 = (const float4*)(agg + (size_t)row0 * HIDDEN);
    float4* xs4 = (float4*)xs;
    if (tid < 4 * HIDDEN / 4) {
        float4 v = a4[tid];
        v.x = fmaxf(v.x, 0.f); v.y = fmaxf(v.y, 0.f);
        v.z = fmaxf(v.z, 0.f); v.w = fmaxf(v.w, 0.f);
        xs4[tid] = v;
    }
    __syncthreads();

    int col = tid & 63;
    int r = tid >> 6;
    float acc = 0.0f;
    #pragma unroll
    for (int k = 0; k < HIDDEN; ++k)
        acc += xs[r][k] * Ws[k * HIDDEN + col];
    hws[(size_t)(row0 + r) * HIDDEN + col] = acc * dinv[row0 + r];
}

// ---------------- CSR pull: agg[d] = b + dinv[d]*(hws[d] + sum_in hws[s]) ----------------
// one wave per node; 4 groups of 16 lanes, each group pulls one edge's row as float4

__global__ __launch_bounds__(256) void pull_k(const int* __restrict__ row_ptr,
                                              const int* __restrict__ csr_src,
                                              const float* __restrict__ dinv,
                                              const float4* __restrict__ hws4,
                                              const float4* __restrict__ b4,
                                              float4* __restrict__ agg4) {
    int node = (blockIdx.x * 256 + threadIdx.x) >> 6;
    int lane = threadIdx.x & 63;
    int g = lane >> 4;    // edge subgroup 0..3
    int fl = lane & 15;   // float4 slot within the 64-float row
    if (node >= N_NODES) return;

    int start = row_ptr[node];
    int end = row_ptr[node + 1];

    float4 acc = make_float4(0.f, 0.f, 0.f, 0.f);
    if (g == 0) acc = hws4[(size_t)node * 16 + fl];  // self-loop term

    for (int i = start; i < end; i += 4) {
        int e = i + g;
        if (e < end) {
            int s = csr_src[e];
            float4 v = hws4[(size_t)s * 16 + fl];
            acc.x += v.x; acc.y += v.y; acc.z += v.z; acc.w += v.w;
        }
    }

    // combine the 4 edge-subgroups (xor lane bits 4 and 5)
    #pragma unroll
    for (int m = 16; m <= 32; m <<= 1) {
        acc.x += __shfl_xor(acc.x, m, 64);
        acc.y += __shfl_xor(acc.y, m, 64);
        acc.z += __shfl_xor(acc.z, m, 64);
        acc.w += __shfl_xor(acc.w, m, 64);
    }

    if (g == 0) {
        float dn = dinv[node];
        float4 bb = b4[fl];
        float4 o;
        o.x = bb.x + dn * acc.x;
        o.y = bb.y + dn * acc.y;
        o.z = bb.z + dn * acc.z;
        o.w = bb.w + dn * acc.w;
        agg4[(size_t)node * 16 + fl] = o;
    }
}

// ---------------- final: out = relu(agg) @ Wl + bl ----------------

__global__ __launch_bounds__(256) void final_k(const float* __restrict__ agg,
                                               const float* __restrict__ Wl,
                                               const float* __restrict__ bl,
                                               float* __restrict__ out) {
    __shared__ float Ws[HIDDEN * N_CLASSES];  // 4 KB
    __shared__ float hs[16][HIDDEN + 1];
    int tid = threadIdx.x;

    if (tid < HIDDEN * N_CLASSES / 4) ((float4*)Ws)[tid] = ((const float4*)Wl)[tid];

    int row0 = blockIdx.x * 16;
    for (int i = tid; i < 16 * HIDDEN; i += 256) {
        int rr = i >> 6;
        int kk = i & 63;
        hs[rr][kk] = fmaxf(agg[(size_t)(row0 + rr) * HIDDEN + kk], 0.0f);
    }
    __syncthreads();

    int col = tid & 15;
    int r = tid >> 4;
    float acc = bl[col];
    #pragma unroll
    for (int k = 0; k < HIDDEN; ++k)
        acc += hs[r][k] * Ws[k * N_CLASSES + col];
    out[(size_t)(row0 + r) * N_CLASSES + col] = acc;
}

// ---------------- launch ----------------

extern "C" void kernel_launch(void* const* d_in, const int* in_sizes, int n_in,
                              void* d_out, int out_size, void* d_ws, size_t ws_size,
                              hipStream_t stream) {
    const float* x  = (const float*)d_in[0];
    const int*   ei = (const int*)d_in[1];   // [2, E]
    const float* W1 = (const float*)d_in[2];
    const float* b1 = (const float*)d_in[3];
    const float* W2 = (const float*)d_in[4];
    const float* b2 = (const float*)d_in[5];
    const float* Wl = (const float*)d_in[6];
    const float* bl = (const float*)d_in[7];
    float* out = (float*)d_out;

    const int* src = ei;
    const int* dst = ei + N_EDGES;

    // workspace layout (16B-aligned chunks, sizes in elements, all multiples of 4)
    float* hws     = (float*)d_ws;                       // N*64
    float* agg     = hws + (size_t)N_NODES * HIDDEN;     // N*64
    int*   csr_src = (int*)(agg + (size_t)N_NODES * HIDDEN);  // E
    int*   deg     = csr_src + N_EDGES;                  // N
    float* dinv    = (float*)(deg + N_NODES);            // N
    int*   row_ptr = (int*)(dinv + N_NODES);             // N+4 (padded)
    int*   cursor  = row_ptr + N_NODES + 4;              // N
    int*   blk_sum = cursor + N_NODES;                   // NB (196 -> pad 200)
    int*   blk_off = blk_sum + 200;                      // NB

    // --- CSR build + normalization ---
    zero_deg_k<<<(N_NODES + 255) / 256, 256, 0, stream>>>(deg);
    hist_k<<<(N_EDGES + 255) / 256, 256, 0, stream>>>(dst, deg);
    dinv_k<<<(N_NODES + 255) / 256, 256, 0, stream>>>(deg, dinv);
    chunk_sum_k<<<NB, 256, 0, stream>>>(deg, blk_sum);
    scan_blocks_k<<<1, 256, 0, stream>>>(blk_sum, blk_off, row_ptr);
    rowptr_k<<<NB, 256, 0, stream>>>(deg, blk_off, row_ptr, cursor);
    fill_k<<<(N_EDGES + 255) / 256, 256, 0, stream>>>(src, dst, cursor, csr_src);

    // --- layer 1 ---
    gemm1_k<<<N_NODES / 4, 256, 0, stream>>>(x, W1, dinv, hws);
    pull_k<<<(N_NODES * 64 + 255) / 256, 256, 0, stream>>>(row_ptr, csr_src, dinv,
                                                           (const float4*)hws,
                                                           (const float4*)b1,
                                                           (float4*)agg);

    // --- layer 2 ---
    gemm2_k<<<N_NODES / 4, 256, 0, stream>>>(agg, W2, dinv, hws);
    pull_k<<<(N_NODES * 64 + 255) / 256, 256, 0, stream>>>(row_ptr, csr_src, dinv,
                                                           (const float4*)hws,
                                                           (const float4*)b2,
                                                           (float4*)agg);

    // --- classifier head ---
    final_k<<<N_NODES / 16, 256, 0, stream>>>(agg, Wl, bl, out);
}

// Round 3
// 526.035 us; speedup vs baseline: 1.9290x; 1.0928x over previous
//
#include <hip/hip_runtime.h>
#include <math.h>

#define N_NODES 100000
#define N_EDGES 1600000
#define IN_FEAT 128
#define HIDDEN 64
#define N_CLASSES 16

#define CHUNK 512
#define NB ((N_NODES + CHUNK - 1) / CHUNK)  // 196

#define NSLICE 8
#define SLICE_SZ ((N_NODES + NSLICE - 1) / NSLICE)  // 12500
#define EPB 1024                                    // edges per block (256 thr x int4)
#define NCHUNK ((N_EDGES + EPB - 1) / EPB)          // 1563

// ---------------- degree / CSR build ----------------

__global__ void zero_deg_k(int* __restrict__ deg) {
    int i = blockIdx.x * blockDim.x + threadIdx.x;
    if (i < N_NODES) deg[i] = 0;
}

__global__ void hist_k(const int* __restrict__ dst, int* __restrict__ deg) {
    int base = (blockIdx.x * 256 + threadIdx.x) * 4;
    if (base >= N_EDGES) return;  // N_EDGES % 4 == 0 -> int4 safe
    int4 d4 = ((const int4*)dst)[base >> 2];
    atomicAdd(&deg[d4.x], 1);
    atomicAdd(&deg[d4.y], 1);
    atomicAdd(&deg[d4.z], 1);
    atomicAdd(&deg[d4.w], 1);
}

__global__ void dinv_k(const int* __restrict__ deg, float* __restrict__ dinv) {
    int i = blockIdx.x * blockDim.x + threadIdx.x;
    if (i < N_NODES) dinv[i] = 1.0f / sqrtf((float)(deg[i] + 1));  // +1 self-loop
}

__global__ __launch_bounds__(256) void chunk_sum_k(const int* __restrict__ deg,
                                                   int* __restrict__ blk_sum) {
    __shared__ int sm[256];
    int b = blockIdx.x, t = threadIdx.x;
    int i0 = b * CHUNK + t;
    int v = 0;
    if (i0 < N_NODES) v += deg[i0];
    if (i0 + 256 < N_NODES) v += deg[i0 + 256];
    sm[t] = v;
    __syncthreads();
    for (int s = 128; s > 0; s >>= 1) {
        if (t < s) sm[t] += sm[t + s];
        __syncthreads();
    }
    if (t == 0) blk_sum[b] = sm[0];
}

__global__ __launch_bounds__(256) void scan_blocks_k(const int* __restrict__ blk_sum,
                                                     int* __restrict__ blk_off,
                                                     int* __restrict__ row_ptr) {
    __shared__ int sm[256];
    int t = threadIdx.x;
    int v = (t < NB) ? blk_sum[t] : 0;
    sm[t] = v;
    __syncthreads();
    for (int s = 1; s < 256; s <<= 1) {
        int add = (t >= s) ? sm[t - s] : 0;
        __syncthreads();
        sm[t] += add;
        __syncthreads();
    }
    if (t < NB) blk_off[t] = sm[t] - v;  // exclusive
    if (t == 0) row_ptr[N_NODES] = N_EDGES;
}

__global__ __launch_bounds__(256) void rowptr_k(const int* __restrict__ deg,
                                                const int* __restrict__ blk_off,
                                                int* __restrict__ row_ptr,
                                                int* __restrict__ cursor) {
    __shared__ int pair[256];
    int b = blockIdx.x, t = threadIdx.x;
    int i0 = b * CHUNK + 2 * t;
    int d0 = (i0 < N_NODES) ? deg[i0] : 0;
    int d1 = (i0 + 1 < N_NODES) ? deg[i0 + 1] : 0;
    int p = d0 + d1;
    pair[t] = p;
    __syncthreads();
    for (int s = 1; s < 256; s <<= 1) {
        int add = (t >= s) ? pair[t - s] : 0;
        __syncthreads();
        pair[t] += add;
        __syncthreads();
    }
    int excl = pair[t] - p + blk_off[b];
    if (i0 < N_NODES)     { row_ptr[i0]     = excl;      cursor[i0]     = excl; }
    if (i0 + 1 < N_NODES) { row_ptr[i0 + 1] = excl + d0; cursor[i0 + 1] = excl + d0; }
}

// XCD-sliced fill: slice = blockIdx&7 rides round-robin block->XCD dispatch so each
// XCD's L2 only sees 1/8 of cursor (50KB) and csr_src (0.8MB) -> stores combine into
// full lines before writeback. Correctness independent of the mapping.
__global__ __launch_bounds__(256) void fill_sliced_k(const int* __restrict__ src,
                                                     const int* __restrict__ dst,
                                                     int* __restrict__ cursor,
                                                     int* __restrict__ csr_src) {
    int slice = blockIdx.x & (NSLICE - 1);
    int chunk = blockIdx.x >> 3;
    int lo = slice * SLICE_SZ;
    int hi = lo + SLICE_SZ;
    int base = chunk * EPB + threadIdx.x * 4;
    if (base >= N_EDGES) return;  // N_EDGES % 4 == 0 -> int4 safe
    int4 d4 = ((const int4*)dst)[base >> 2];
    int4 s4 = ((const int4*)src)[base >> 2];
    #pragma unroll
    for (int j = 0; j < 4; ++j) {
        int d = (j == 0) ? d4.x : (j == 1) ? d4.y : (j == 2) ? d4.z : d4.w;
        int s = (j == 0) ? s4.x : (j == 1) ? s4.y : (j == 2) ? s4.z : s4.w;
        if (d >= lo && d < hi) {
            int pos = atomicAdd(&cursor[d], 1);
            csr_src[pos] = s;
        }
    }
}

// ---------------- GEMM 1: hws = (x @ W1) * dinv[row]   [N,128]x[128,64] ----------------

__global__ __launch_bounds__(256) void gemm1_k(const float* __restrict__ x,
                                               const float* __restrict__ W,
                                               const float* __restrict__ dinv,
                                               float* __restrict__ hws) {
    __shared__ float Ws[IN_FEAT * HIDDEN];  // 32 KB
    __shared__ float xs[4][IN_FEAT];
    int tid = threadIdx.x;

    const float4* W4 = (const float4*)W;
    float4* Ws4 = (float4*)Ws;
    #pragma unroll
    for (int i = 0; i < (IN_FEAT * HIDDEN / 4) / 256; ++i)
        Ws4[tid + i * 256] = W4[tid + i * 256];

    int row0 = blockIdx.x * 4;
    const float4* x4 = (const float4*)(x + (size_t)row0 * IN_FEAT);
    float4* xs4 = (float4*)xs;
    if (tid < 4 * IN_FEAT / 4) xs4[tid] = x4[tid];
    __syncthreads();

    int col = tid & 63;
    int r = tid >> 6;
    float acc = 0.0f;
    #pragma unroll 16
    for (int k = 0; k < IN_FEAT; ++k)
        acc += xs[r][k] * Ws[k * HIDDEN + col];
    hws[(size_t)(row0 + r) * HIDDEN + col] = acc * dinv[row0 + r];
}

// ---------------- GEMM 2: hws = (relu(agg) @ W2) * dinv[row] ----------------

__global__ __launch_bounds__(256) void gemm2_k(const float* __restrict__ agg,
                                               const float* __restrict__ W,
                                               const float* __restrict__ dinv,
                                               float* __restrict__ hws) {
    __shared__ float Ws[HIDDEN * HIDDEN];  // 16 KB
    __shared__ float xs[4][HIDDEN];
    int tid = threadIdx.x;

    const float4* W4 = (const float4*)W;
    float4* Ws4 = (float4*)Ws;
    #pragma unroll
    for (int i = 0; i < (HIDDEN * HIDDEN / 4) / 256; ++i)
        Ws4[tid + i * 256] = W4[tid + i * 256];

    int row0 = blockIdx.x * 4;
    const float4* a4 = (const float4*)(agg + (size_t)row0 * HIDDEN);
    float4* xs4 = (float4*)xs;
    if (tid < 4 * HIDDEN / 4) {
        float4 v = a4[tid];
        v.x = fmaxf(v.x, 0.f); v.y = fmaxf(v.y, 0.f);
        v.z = fmaxf(v.z, 0.f); v.w = fmaxf(v.w, 0.f);
        xs4[tid] = v;
    }
    __syncthreads();

    int col = tid & 63;
    int r = tid >> 6;
    float acc = 0.0f;
    #pragma unroll
    for (int k = 0; k < HIDDEN; ++k)
        acc += xs[r][k] * Ws[k * HIDDEN + col];
    hws[(size_t)(row0 + r) * HIDDEN + col] = acc * dinv[row0 + r];
}

// ---------------- CSR pull: agg[d] = b + dinv[d]*(hws[d] + sum_in hws[s]) ----------------

__global__ __launch_bounds__(256) void pull_k(const int* __restrict__ row_ptr,
                                              const int* __restrict__ csr_src,
                                              const float* __restrict__ dinv,
                                              const float4* __restrict__ hws4,
                                              const float4* __restrict__ b4,
                                              float4* __restrict__ agg4) {
    int node = (blockIdx.x * 256 + threadIdx.x) >> 6;
    int lane = threadIdx.x & 63;
    int g = lane >> 4;    // edge subgroup 0..3
    int fl = lane & 15;   // float4 slot within the 64-float row
    if (node >= N_NODES) return;

    int start = row_ptr[node];
    int end = row_ptr[node + 1];

    float4 acc = make_float4(0.f, 0.f, 0.f, 0.f);
    if (g == 0) acc = hws4[(size_t)node * 16 + fl];  // self-loop term

    for (int i = start; i < end; i += 4) {
        int e = i + g;
        if (e < end) {
            int s = csr_src[e];
            float4 v = hws4[(size_t)s * 16 + fl];
            acc.x += v.x; acc.y += v.y; acc.z += v.z; acc.w += v.w;
        }
    }

    #pragma unroll
    for (int m = 16; m <= 32; m <<= 1) {
        acc.x += __shfl_xor(acc.x, m, 64);
        acc.y += __shfl_xor(acc.y, m, 64);
        acc.z += __shfl_xor(acc.z, m, 64);
        acc.w += __shfl_xor(acc.w, m, 64);
    }

    if (g == 0) {
        float dn = dinv[node];
        float4 bb = b4[fl];
        float4 o;
        o.x = bb.x + dn * acc.x;
        o.y = bb.y + dn * acc.y;
        o.z = bb.z + dn * acc.z;
        o.w = bb.w + dn * acc.w;
        agg4[(size_t)node * 16 + fl] = o;
    }
}

// ---------------- final: out = relu(agg) @ Wl + bl ----------------

__global__ __launch_bounds__(256) void final_k(const float* __restrict__ agg,
                                               const float* __restrict__ Wl,
                                               const float* __restrict__ bl,
                                               float* __restrict__ out) {
    __shared__ float Ws[HIDDEN * N_CLASSES];  // 4 KB
    __shared__ float hs[16][HIDDEN + 1];
    int tid = threadIdx.x;

    if (tid < HIDDEN * N_CLASSES / 4) ((float4*)Ws)[tid] = ((const float4*)Wl)[tid];

    int row0 = blockIdx.x * 16;
    for (int i = tid; i < 16 * HIDDEN; i += 256) {
        int rr = i >> 6;
        int kk = i & 63;
        hs[rr][kk] = fmaxf(agg[(size_t)(row0 + rr) * HIDDEN + kk], 0.0f);
    }
    __syncthreads();

    int col = tid & 15;
    int r = tid >> 4;
    float acc = bl[col];
    #pragma unroll
    for (int k = 0; k < HIDDEN; ++k)
        acc += hs[r][k] * Ws[k * N_CLASSES + col];
    out[(size_t)(row0 + r) * N_CLASSES + col] = acc;
}

// ---------------- launch ----------------

extern "C" void kernel_launch(void* const* d_in, const int* in_sizes, int n_in,
                              void* d_out, int out_size, void* d_ws, size_t ws_size,
                              hipStream_t stream) {
    const float* x  = (const float*)d_in[0];
    const int*   ei = (const int*)d_in[1];   // [2, E]
    const float* W1 = (const float*)d_in[2];
    const float* b1 = (const float*)d_in[3];
    const float* W2 = (const float*)d_in[4];
    const float* b2 = (const float*)d_in[5];
    const float* Wl = (const float*)d_in[6];
    const float* bl = (const float*)d_in[7];
    float* out = (float*)d_out;

    const int* src = ei;
    const int* dst = ei + N_EDGES;

    // workspace layout
    float* hws     = (float*)d_ws;                       // N*64
    float* agg     = hws + (size_t)N_NODES * HIDDEN;     // N*64
    int*   csr_src = (int*)(agg + (size_t)N_NODES * HIDDEN);  // E
    int*   deg     = csr_src + N_EDGES;                  // N
    float* dinv    = (float*)(deg + N_NODES);            // N
    int*   row_ptr = (int*)(dinv + N_NODES);             // N+4 (padded)
    int*   cursor  = row_ptr + N_NODES + 4;              // N
    int*   blk_sum = cursor + N_NODES;                   // NB (pad 200)
    int*   blk_off = blk_sum + 200;                      // NB

    // --- CSR build + normalization ---
    zero_deg_k<<<(N_NODES + 255) / 256, 256, 0, stream>>>(deg);
    hist_k<<<(N_EDGES / 4 + 255) / 256, 256, 0, stream>>>(dst, deg);
    dinv_k<<<(N_NODES + 255) / 256, 256, 0, stream>>>(deg, dinv);
    chunk_sum_k<<<NB, 256, 0, stream>>>(deg, blk_sum);
    scan_blocks_k<<<1, 256, 0, stream>>>(blk_sum, blk_off, row_ptr);
    rowptr_k<<<NB, 256, 0, stream>>>(deg, blk_off, row_ptr, cursor);
    fill_sliced_k<<<NCHUNK * NSLICE, 256, 0, stream>>>(src, dst, cursor, csr_src);

    // --- layer 1 ---
    gemm1_k<<<N_NODES / 4, 256, 0, stream>>>(x, W1, dinv, hws);
    pull_k<<<(N_NODES * 64 + 255) / 256, 256, 0, stream>>>(row_ptr, csr_src, dinv,
                                                           (const float4*)hws,
                                                           (const float4*)b1,
                                                           (float4*)agg);

    // --- layer 2 ---
    gemm2_k<<<N_NODES / 4, 256, 0, stream>>>(agg, W2, dinv, hws);
    pull_k<<<(N_NODES * 64 + 255) / 256, 256, 0, stream>>>(row_ptr, csr_src, dinv,
                                                           (const float4*)hws,
                                                           (const float4*)b2,
                                                           (float4*)agg);

    // --- classifier head ---
    final_k<<<N_NODES / 16, 256, 0, stream>>>(agg, Wl, bl, out);
}

// Round 4
// 443.937 us; speedup vs baseline: 2.2858x; 1.1849x over previous
//
#include <hip/hip_runtime.h>
#include <math.h>

#define N_NODES 100000
#define N_EDGES 1600000
#define IN_FEAT 128
#define HIDDEN 64
#define N_CLASSES 16

#define CHUNK 512
#define NB ((N_NODES + CHUNK - 1) / CHUNK)  // 196

#define NSLICE 8
#define SLICE_SZ ((N_NODES + NSLICE - 1) / NSLICE)  // 12500
#define EPB 1024
#define NCHUNK ((N_EDGES + EPB - 1) / EPB)

#define TM 64
#define GBLK ((N_NODES + TM - 1) / TM)  // 1563

// ---------------- degree / CSR build ----------------

__global__ void zero_deg_k(int* __restrict__ deg) {
    int i = blockIdx.x * blockDim.x + threadIdx.x;
    if (i < N_NODES) deg[i] = 0;
}

__global__ void hist_k(const int* __restrict__ dst, int* __restrict__ deg) {
    int base = (blockIdx.x * 256 + threadIdx.x) * 4;
    if (base >= N_EDGES) return;
    int4 d4 = ((const int4*)dst)[base >> 2];
    atomicAdd(&deg[d4.x], 1);
    atomicAdd(&deg[d4.y], 1);
    atomicAdd(&deg[d4.z], 1);
    atomicAdd(&deg[d4.w], 1);
}

__global__ void dinv_k(const int* __restrict__ deg, float* __restrict__ dinv) {
    int i = blockIdx.x * blockDim.x + threadIdx.x;
    if (i < N_NODES) dinv[i] = 1.0f / sqrtf((float)(deg[i] + 1));
}

__global__ __launch_bounds__(256) void chunk_sum_k(const int* __restrict__ deg,
                                                   int* __restrict__ blk_sum) {
    __shared__ int sm[256];
    int b = blockIdx.x, t = threadIdx.x;
    int i0 = b * CHUNK + t;
    int v = 0;
    if (i0 < N_NODES) v += deg[i0];
    if (i0 + 256 < N_NODES) v += deg[i0 + 256];
    sm[t] = v;
    __syncthreads();
    for (int s = 128; s > 0; s >>= 1) {
        if (t < s) sm[t] += sm[t + s];
        __syncthreads();
    }
    if (t == 0) blk_sum[b] = sm[0];
}

__global__ __launch_bounds__(256) void scan_blocks_k(const int* __restrict__ blk_sum,
                                                     int* __restrict__ blk_off,
                                                     int* __restrict__ row_ptr) {
    __shared__ int sm[256];
    int t = threadIdx.x;
    int v = (t < NB) ? blk_sum[t] : 0;
    sm[t] = v;
    __syncthreads();
    for (int s = 1; s < 256; s <<= 1) {
        int add = (t >= s) ? sm[t - s] : 0;
        __syncthreads();
        sm[t] += add;
        __syncthreads();
    }
    if (t < NB) blk_off[t] = sm[t] - v;
    if (t == 0) row_ptr[N_NODES] = N_EDGES;
}

__global__ __launch_bounds__(256) void rowptr_k(const int* __restrict__ deg,
                                                const int* __restrict__ blk_off,
                                                int* __restrict__ row_ptr,
                                                int* __restrict__ cursor) {
    __shared__ int pair[256];
    int b = blockIdx.x, t = threadIdx.x;
    int i0 = b * CHUNK + 2 * t;
    int d0 = (i0 < N_NODES) ? deg[i0] : 0;
    int d1 = (i0 + 1 < N_NODES) ? deg[i0 + 1] : 0;
    int p = d0 + d1;
    pair[t] = p;
    __syncthreads();
    for (int s = 1; s < 256; s <<= 1) {
        int add = (t >= s) ? pair[t - s] : 0;
        __syncthreads();
        pair[t] += add;
        __syncthreads();
    }
    int excl = pair[t] - p + blk_off[b];
    if (i0 < N_NODES)     { row_ptr[i0]     = excl;      cursor[i0]     = excl; }
    if (i0 + 1 < N_NODES) { row_ptr[i0 + 1] = excl + d0; cursor[i0 + 1] = excl + d0; }
}

__global__ __launch_bounds__(256) void fill_sliced_k(const int* __restrict__ src,
                                                     const int* __restrict__ dst,
                                                     int* __restrict__ cursor,
                                                     int* __restrict__ csr_src) {
    int slice = blockIdx.x & (NSLICE - 1);
    int chunk = blockIdx.x >> 3;
    int lo = slice * SLICE_SZ;
    int hi = lo + SLICE_SZ;
    int base = chunk * EPB + threadIdx.x * 4;
    if (base >= N_EDGES) return;
    int4 d4 = ((const int4*)dst)[base >> 2];
    int4 s4 = ((const int4*)src)[base >> 2];
    #pragma unroll
    for (int j = 0; j < 4; ++j) {
        int d = (j == 0) ? d4.x : (j == 1) ? d4.y : (j == 2) ? d4.z : d4.w;
        int s = (j == 0) ? s4.x : (j == 1) ? s4.y : (j == 2) ? s4.z : s4.w;
        if (d >= lo && d < hi) {
            int pos = atomicAdd(&cursor[d], 1);
            csr_src[pos] = s;
        }
    }
}

// ---------------- register-tiled GEMM 1: hws = (x @ W1) * dinv[row] ----------------
// 64x64 tile/block, 4x4 acc/thread, x staged k-major (xt[k][row], stride 68:
// 16B-aligned b128, banks 4*rgrp -> conflict-free). Inner iter: 2 ds_read_b128 / 16 FMA.

__global__ __launch_bounds__(256) void gemm1_tiled_k(const float* __restrict__ x,
                                                     const float* __restrict__ W,
                                                     const float* __restrict__ dinv,
                                                     float* __restrict__ hws) {
    __shared__ float Ws[64][64];  // 16 KB: k-slice rows x 64 cols
    __shared__ float xt[64][68];  // 17.4 KB: k x row, padded stride 68
    int tid = threadIdx.x;
    int row0 = blockIdx.x * TM;
    int rgrp4 = (tid >> 4) * 4;  // row offset 0..60
    int cgrp4 = (tid & 15) * 4;  // col offset 0..60

    float acc[4][4];
    #pragma unroll
    for (int r = 0; r < 4; ++r)
        #pragma unroll
        for (int c = 0; c < 4; ++c) acc[r][c] = 0.0f;

    for (int k0 = 0; k0 < IN_FEAT; k0 += 64) {
        #pragma unroll
        for (int i = 0; i < 4; ++i) {  // stage W k-slice (4096 floats)
            int f4 = tid + i * 256;
            int kk = f4 >> 4, c4 = (f4 & 15) * 4;
            *(float4*)&Ws[kk][c4] = *(const float4*)&W[(size_t)(k0 + kk) * HIDDEN + c4];
        }
        #pragma unroll
        for (int i = 0; i < 4; ++i) {  // stage x slice transposed
            int f4 = tid + i * 256;
            int rr = f4 >> 4, kq = (f4 & 15) * 4;
            int row = row0 + rr;
            if (row >= N_NODES) row = N_NODES - 1;  // clamp; store is guarded
            float4 v = *(const float4*)&x[(size_t)row * IN_FEAT + k0 + kq];
            xt[kq + 0][rr] = v.x; xt[kq + 1][rr] = v.y;
            xt[kq + 2][rr] = v.z; xt[kq + 3][rr] = v.w;
        }
        __syncthreads();

        #pragma unroll 16
        for (int kk = 0; kk < 64; ++kk) {
            float4 a = *(const float4*)&xt[kk][rgrp4];
            float4 b = *(const float4*)&Ws[kk][cgrp4];
            acc[0][0] += a.x * b.x; acc[0][1] += a.x * b.y; acc[0][2] += a.x * b.z; acc[0][3] += a.x * b.w;
            acc[1][0] += a.y * b.x; acc[1][1] += a.y * b.y; acc[1][2] += a.y * b.z; acc[1][3] += a.y * b.w;
            acc[2][0] += a.z * b.x; acc[2][1] += a.z * b.y; acc[2][2] += a.z * b.z; acc[2][3] += a.z * b.w;
            acc[3][0] += a.w * b.x; acc[3][1] += a.w * b.y; acc[3][2] += a.w * b.z; acc[3][3] += a.w * b.w;
        }
        __syncthreads();
    }

    #pragma unroll
    for (int r = 0; r < 4; ++r) {
        int row = row0 + rgrp4 + r;
        if (row < N_NODES) {
            float dn = dinv[row];
            float4 o = make_float4(acc[r][0] * dn, acc[r][1] * dn, acc[r][2] * dn, acc[r][3] * dn);
            *(float4*)&hws[(size_t)row * HIDDEN + cgrp4] = o;
        }
    }
}

// ---------------- register-tiled GEMM 2: hws = (relu(agg) @ W2) * dinv[row] ----------------

__global__ __launch_bounds__(256) void gemm2_tiled_k(const float* __restrict__ agg,
                                                     const float* __restrict__ W,
                                                     const float* __restrict__ dinv,
                                                     float* __restrict__ hws) {
    __shared__ float Ws[64][64];
    __shared__ float xt[64][68];
    int tid = threadIdx.x;
    int row0 = blockIdx.x * TM;
    int rgrp4 = (tid >> 4) * 4;
    int cgrp4 = (tid & 15) * 4;

    #pragma unroll
    for (int i = 0; i < 4; ++i) {
        int f4 = tid + i * 256;
        int kk = f4 >> 4, c4 = (f4 & 15) * 4;
        *(float4*)&Ws[kk][c4] = *(const float4*)&W[(size_t)kk * HIDDEN + c4];
    }
    #pragma unroll
    for (int i = 0; i < 4; ++i) {
        int f4 = tid + i * 256;
        int rr = f4 >> 4, kq = (f4 & 15) * 4;
        int row = row0 + rr;
        if (row >= N_NODES) row = N_NODES - 1;
        float4 v = *(const float4*)&agg[(size_t)row * HIDDEN + kq];
        xt[kq + 0][rr] = fmaxf(v.x, 0.f); xt[kq + 1][rr] = fmaxf(v.y, 0.f);
        xt[kq + 2][rr] = fmaxf(v.z, 0.f); xt[kq + 3][rr] = fmaxf(v.w, 0.f);
    }
    __syncthreads();

    float acc[4][4];
    #pragma unroll
    for (int r = 0; r < 4; ++r)
        #pragma unroll
        for (int c = 0; c < 4; ++c) acc[r][c] = 0.0f;

    #pragma unroll 16
    for (int kk = 0; kk < 64; ++kk) {
        float4 a = *(const float4*)&xt[kk][rgrp4];
        float4 b = *(const float4*)&Ws[kk][cgrp4];
        acc[0][0] += a.x * b.x; acc[0][1] += a.x * b.y; acc[0][2] += a.x * b.z; acc[0][3] += a.x * b.w;
        acc[1][0] += a.y * b.x; acc[1][1] += a.y * b.y; acc[1][2] += a.y * b.z; acc[1][3] += a.y * b.w;
        acc[2][0] += a.z * b.x; acc[2][1] += a.z * b.y; acc[2][2] += a.z * b.z; acc[2][3] += a.z * b.w;
        acc[3][0] += a.w * b.x; acc[3][1] += a.w * b.y; acc[3][2] += a.w * b.z; acc[3][3] += a.w * b.w;
    }

    #pragma unroll
    for (int r = 0; r < 4; ++r) {
        int row = row0 + rgrp4 + r;
        if (row < N_NODES) {
            float dn = dinv[row];
            float4 o = make_float4(acc[r][0] * dn, acc[r][1] * dn, acc[r][2] * dn, acc[r][3] * dn);
            *(float4*)&hws[(size_t)row * HIDDEN + cgrp4] = o;
        }
    }
}

// ---------------- CSR pull: agg[d] = b + dinv[d]*(hws[d] + sum_in hws[s]) ----------------

__global__ __launch_bounds__(256) void pull_k(const int* __restrict__ row_ptr,
                                              const int* __restrict__ csr_src,
                                              const float* __restrict__ dinv,
                                              const float4* __restrict__ hws4,
                                              const float4* __restrict__ b4,
                                              float4* __restrict__ agg4) {
    int node = (blockIdx.x * 256 + threadIdx.x) >> 6;
    int lane = threadIdx.x & 63;
    int g = lane >> 4;
    int fl = lane & 15;
    if (node >= N_NODES) return;

    int start = row_ptr[node];
    int end = row_ptr[node + 1];

    float4 acc = make_float4(0.f, 0.f, 0.f, 0.f);
    if (g == 0) acc = hws4[(size_t)node * 16 + fl];

    for (int i = start; i < end; i += 4) {
        int e = i + g;
        if (e < end) {
            int s = csr_src[e];
            float4 v = hws4[(size_t)s * 16 + fl];
            acc.x += v.x; acc.y += v.y; acc.z += v.z; acc.w += v.w;
        }
    }

    #pragma unroll
    for (int m = 16; m <= 32; m <<= 1) {
        acc.x += __shfl_xor(acc.x, m, 64);
        acc.y += __shfl_xor(acc.y, m, 64);
        acc.z += __shfl_xor(acc.z, m, 64);
        acc.w += __shfl_xor(acc.w, m, 64);
    }

    if (g == 0) {
        float dn = dinv[node];
        float4 bb = b4[fl];
        float4 o;
        o.x = bb.x + dn * acc.x;
        o.y = bb.y + dn * acc.y;
        o.z = bb.z + dn * acc.z;
        o.w = bb.w + dn * acc.w;
        agg4[(size_t)node * 16 + fl] = o;
    }
}

// ---------------- final: out = relu(agg) @ Wl + bl ----------------

__global__ __launch_bounds__(256) void final_k(const float* __restrict__ agg,
                                               const float* __restrict__ Wl,
                                               const float* __restrict__ bl,
                                               float* __restrict__ out) {
    __shared__ float Ws[HIDDEN * N_CLASSES];
    __shared__ float hs[16][HIDDEN + 1];
    int tid = threadIdx.x;

    if (tid < HIDDEN * N_CLASSES / 4) ((float4*)Ws)[tid] = ((const float4*)Wl)[tid];

    int row0 = blockIdx.x * 16;
    for (int i = tid; i < 16 * HIDDEN; i += 256) {
        int rr = i >> 6;
        int kk = i & 63;
        hs[rr][kk] = fmaxf(agg[(size_t)(row0 + rr) * HIDDEN + kk], 0.0f);
    }
    __syncthreads();

    int col = tid & 15;
    int r = tid >> 4;
    float acc = bl[col];
    #pragma unroll
    for (int k = 0; k < HIDDEN; ++k)
        acc += hs[r][k] * Ws[k * N_CLASSES + col];
    out[(size_t)(row0 + r) * N_CLASSES + col] = acc;
}

// ---------------- launch ----------------

extern "C" void kernel_launch(void* const* d_in, const int* in_sizes, int n_in,
                              void* d_out, int out_size, void* d_ws, size_t ws_size,
                              hipStream_t stream) {
    const float* x  = (const float*)d_in[0];
    const int*   ei = (const int*)d_in[1];
    const float* W1 = (const float*)d_in[2];
    const float* b1 = (const float*)d_in[3];
    const float* W2 = (const float*)d_in[4];
    const float* b2 = (const float*)d_in[5];
    const float* Wl = (const float*)d_in[6];
    const float* bl = (const float*)d_in[7];
    float* out = (float*)d_out;

    const int* src = ei;
    const int* dst = ei + N_EDGES;

    float* hws     = (float*)d_ws;
    float* agg     = hws + (size_t)N_NODES * HIDDEN;
    int*   csr_src = (int*)(agg + (size_t)N_NODES * HIDDEN);
    int*   deg     = csr_src + N_EDGES;
    float* dinv    = (float*)(deg + N_NODES);
    int*   row_ptr = (int*)(dinv + N_NODES);
    int*   cursor  = row_ptr + N_NODES + 4;
    int*   blk_sum = cursor + N_NODES;
    int*   blk_off = blk_sum + 200;

    // --- CSR build + normalization ---
    zero_deg_k<<<(N_NODES + 255) / 256, 256, 0, stream>>>(deg);
    hist_k<<<(N_EDGES / 4 + 255) / 256, 256, 0, stream>>>(dst, deg);
    dinv_k<<<(N_NODES + 255) / 256, 256, 0, stream>>>(deg, dinv);
    chunk_sum_k<<<NB, 256, 0, stream>>>(deg, blk_sum);
    scan_blocks_k<<<1, 256, 0, stream>>>(blk_sum, blk_off, row_ptr);
    rowptr_k<<<NB, 256, 0, stream>>>(deg, blk_off, row_ptr, cursor);
    fill_sliced_k<<<NCHUNK * NSLICE, 256, 0, stream>>>(src, dst, cursor, csr_src);

    // --- layer 1 ---
    gemm1_tiled_k<<<GBLK, 256, 0, stream>>>(x, W1, dinv, hws);
    pull_k<<<(N_NODES * 64 + 255) / 256, 256, 0, stream>>>(row_ptr, csr_src, dinv,
                                                           (const float4*)hws,
                                                           (const float4*)b1,
                                                           (float4*)agg);

    // --- layer 2 ---
    gemm2_tiled_k<<<GBLK, 256, 0, stream>>>(agg, W2, dinv, hws);
    pull_k<<<(N_NODES * 64 + 255) / 256, 256, 0, stream>>>(row_ptr, csr_src, dinv,
                                                           (const float4*)hws,
                                                           (const float4*)b2,
                                                           (float4*)agg);

    // --- classifier head ---
    final_k<<<N_NODES / 16, 256, 0, stream>>>(agg, Wl, bl, out);
}

// Round 5
// 408.842 us; speedup vs baseline: 2.4820x; 1.0858x over previous
//
#include <hip/hip_runtime.h>
#include <math.h>

#define N_NODES 100000
#define N_EDGES 1600000
#define IN_FEAT 128
#define HIDDEN 64
#define N_CLASSES 16

#define CHUNK 512
#define NB ((N_NODES + CHUNK - 1) / CHUNK)  // 196

#define NSLICE 8
#define SLICE_SZ ((N_NODES + NSLICE - 1) / NSLICE)  // 12500
#define EPB 1024
#define NCHUNK ((N_EDGES + EPB - 1) / EPB)

#define TM 64
#define GBLK ((N_NODES + TM - 1) / TM)  // 1563

#define NBUK 196                        // buckets of 512 nodes (dst>>9)
#define CB 4096                         // edges per coarse block
#define NCB ((N_EDGES + CB - 1) / CB)   // 391

// ---------------- degree ----------------

__global__ void zero_deg_k(int* __restrict__ deg) {
    int i = blockIdx.x * blockDim.x + threadIdx.x;
    if (i < N_NODES) deg[i] = 0;
}

// XCD-sliced histogram: atomics on a 50KB deg slice stay XCD-local.
__global__ __launch_bounds__(256) void hist_sliced_k(const int* __restrict__ dst,
                                                     int* __restrict__ deg) {
    int slice = blockIdx.x & (NSLICE - 1);
    int chunk = blockIdx.x >> 3;
    int lo = slice * SLICE_SZ;
    int hi = lo + SLICE_SZ;
    int base = chunk * EPB + threadIdx.x * 4;
    if (base >= N_EDGES) return;
    int4 d4 = ((const int4*)dst)[base >> 2];
    if (d4.x >= lo && d4.x < hi) atomicAdd(&deg[d4.x], 1);
    if (d4.y >= lo && d4.y < hi) atomicAdd(&deg[d4.y], 1);
    if (d4.z >= lo && d4.z < hi) atomicAdd(&deg[d4.z], 1);
    if (d4.w >= lo && d4.w < hi) atomicAdd(&deg[d4.w], 1);
}

__global__ void dinv_k(const int* __restrict__ deg, float* __restrict__ dinv) {
    int i = blockIdx.x * blockDim.x + threadIdx.x;
    if (i < N_NODES) dinv[i] = 1.0f / sqrtf((float)(deg[i] + 1));
}

// ---------------- row_ptr (hierarchical scan) ----------------

__global__ __launch_bounds__(256) void chunk_sum_k(const int* __restrict__ deg,
                                                   int* __restrict__ blk_sum) {
    __shared__ int sm[256];
    int b = blockIdx.x, t = threadIdx.x;
    int i0 = b * CHUNK + t;
    int v = 0;
    if (i0 < N_NODES) v += deg[i0];
    if (i0 + 256 < N_NODES) v += deg[i0 + 256];
    sm[t] = v;
    __syncthreads();
    for (int s = 128; s > 0; s >>= 1) {
        if (t < s) sm[t] += sm[t + s];
        __syncthreads();
    }
    if (t == 0) blk_sum[b] = sm[0];
}

__global__ __launch_bounds__(256) void scan_blocks_k(const int* __restrict__ blk_sum,
                                                     int* __restrict__ blk_off,
                                                     int* __restrict__ row_ptr) {
    __shared__ int sm[256];
    int t = threadIdx.x;
    int v = (t < NB) ? blk_sum[t] : 0;
    sm[t] = v;
    __syncthreads();
    for (int s = 1; s < 256; s <<= 1) {
        int add = (t >= s) ? sm[t - s] : 0;
        __syncthreads();
        sm[t] += add;
        __syncthreads();
    }
    if (t < NB) blk_off[t] = sm[t] - v;
    if (t == 0) row_ptr[N_NODES] = N_EDGES;
}

__global__ __launch_bounds__(256) void rowptr_k(const int* __restrict__ deg,
                                                const int* __restrict__ blk_off,
                                                int* __restrict__ row_ptr) {
    __shared__ int pair[256];
    int b = blockIdx.x, t = threadIdx.x;
    int i0 = b * CHUNK + 2 * t;
    int d0 = (i0 < N_NODES) ? deg[i0] : 0;
    int d1 = (i0 + 1 < N_NODES) ? deg[i0 + 1] : 0;
    int p = d0 + d1;
    pair[t] = p;
    __syncthreads();
    for (int s = 1; s < 256; s <<= 1) {
        int add = (t >= s) ? pair[t - s] : 0;
        __syncthreads();
        pair[t] += add;
        __syncthreads();
    }
    int excl = pair[t] - p + blk_off[b];
    if (i0 < N_NODES)     row_ptr[i0]     = excl;
    if (i0 + 1 < N_NODES) row_ptr[i0 + 1] = excl + d0;
}

__global__ void bcur_init_k(const int* __restrict__ row_ptr, int* __restrict__ bcur) {
    int b = blockIdx.x * blockDim.x + threadIdx.x;
    if (b < NBUK) bcur[b] = row_ptr[b * 512];
}

// ---------------- coarse partition: group edges by 512-node bucket ----------------
// Per-block LDS counting sort over 196 buckets; one global atomic per (block,bucket)
// reserves space; copy-out is contiguous per bucket (~170B segments).

__global__ __launch_bounds__(256) void coarse_k(const int* __restrict__ src,
                                                const int* __restrict__ dst,
                                                int* __restrict__ bcur,
                                                int2* __restrict__ pairs) {
    __shared__ int hist[NBUK + 4], loff[NBUK + 4], cur[NBUK + 4], gbase[NBUK + 4];
    __shared__ int sc[256];
    __shared__ int2 stage[CB];  // 32 KB
    int tid = threadIdx.x;
    int eb = blockIdx.x * CB;
    int nvalid = N_EDGES - eb;
    if (nvalid > CB) nvalid = CB;

    if (tid < NBUK) hist[tid] = 0;
    __syncthreads();

    int4 s4[4], d4[4];
    #pragma unroll
    for (int q = 0; q < 4; ++q) {
        int e4 = (eb >> 2) + tid + q * 256;  // int4 index; N_EDGES%4==0
        if (e4 * 4 < N_EDGES) {
            s4[q] = ((const int4*)src)[e4];
            d4[q] = ((const int4*)dst)[e4];
        } else {
            d4[q] = make_int4(-1, -1, -1, -1);  // sentinel
            s4[q] = make_int4(0, 0, 0, 0);
        }
    }
    #pragma unroll
    for (int q = 0; q < 4; ++q) {
        if (d4[q].x >= 0) {
            atomicAdd(&hist[d4[q].x >> 9], 1);
            atomicAdd(&hist[d4[q].y >> 9], 1);
            atomicAdd(&hist[d4[q].z >> 9], 1);
            atomicAdd(&hist[d4[q].w >> 9], 1);
        }
    }
    __syncthreads();

    // exclusive scan of hist
    int v = (tid < NBUK) ? hist[tid] : 0;
    sc[tid] = v;
    __syncthreads();
    for (int s = 1; s < 256; s <<= 1) {
        int add = (tid >= s) ? sc[tid - s] : 0;
        __syncthreads();
        sc[tid] += add;
        __syncthreads();
    }
    if (tid < NBUK) {
        int excl = sc[tid] - v;
        loff[tid] = excl;
        cur[tid] = excl;
        gbase[tid] = atomicAdd(&bcur[tid], v);
    }
    __syncthreads();

    // local scatter grouped by bucket
    #pragma unroll
    for (int q = 0; q < 4; ++q) {
        if (d4[q].x >= 0) {
            int b, r;
            b = d4[q].x >> 9; r = atomicAdd(&cur[b], 1); stage[r] = make_int2(s4[q].x, d4[q].x);
            b = d4[q].y >> 9; r = atomicAdd(&cur[b], 1); stage[r] = make_int2(s4[q].y, d4[q].y);
            b = d4[q].z >> 9; r = atomicAdd(&cur[b], 1); stage[r] = make_int2(s4[q].z, d4[q].z);
            b = d4[q].w >> 9; r = atomicAdd(&cur[b], 1); stage[r] = make_int2(s4[q].w, d4[q].w);
        }
    }
    __syncthreads();

    // copy out: consecutive slots of one bucket -> consecutive global positions
    for (int i = tid; i < nvalid; i += 256) {
        int2 p = stage[i];
        int b = p.y >> 9;
        pairs[gbase[b] + (i - loff[b])] = p;
    }
}

// ---------------- fine fill: per-bucket CSR placement ----------------
// One block owns one bucket: LDS cursors (init from row_ptr), scattered stores
// confined to this block's ~32KB csr_src region -> L2 write-combined.

__global__ __launch_bounds__(256) void fine_k(const int2* __restrict__ pairs,
                                              const int* __restrict__ row_ptr,
                                              int* __restrict__ csr_src) {
    __shared__ int cur[512];
    int b = blockIdx.x;
    int node0 = b * 512;
    int nn = N_NODES - node0;
    if (nn > 512) nn = 512;
    int tid = threadIdx.x;
    for (int j = tid; j < nn; j += 256) cur[j] = row_ptr[node0 + j];
    __syncthreads();
    int e0 = row_ptr[node0];
    int e1 = row_ptr[node0 + nn];
    for (int e = e0 + tid; e < e1; e += 256) {
        int2 p = pairs[e];
        int pos = atomicAdd(&cur[p.y - node0], 1);
        csr_src[pos] = p.x;
    }
}

// ---------------- register-tiled GEMM 1: hws = (x @ W1) * dinv[row] ----------------

__global__ __launch_bounds__(256) void gemm1_tiled_k(const float* __restrict__ x,
                                                     const float* __restrict__ W,
                                                     const float* __restrict__ dinv,
                                                     float* __restrict__ hws) {
    __shared__ float Ws[64][64];
    __shared__ float xt[64][68];
    int tid = threadIdx.x;
    int row0 = blockIdx.x * TM;
    int rgrp4 = (tid >> 4) * 4;
    int cgrp4 = (tid & 15) * 4;

    float acc[4][4];
    #pragma unroll
    for (int r = 0; r < 4; ++r)
        #pragma unroll
        for (int c = 0; c < 4; ++c) acc[r][c] = 0.0f;

    for (int k0 = 0; k0 < IN_FEAT; k0 += 64) {
        #pragma unroll
        for (int i = 0; i < 4; ++i) {
            int f4 = tid + i * 256;
            int kk = f4 >> 4, c4 = (f4 & 15) * 4;
            *(float4*)&Ws[kk][c4] = *(const float4*)&W[(size_t)(k0 + kk) * HIDDEN + c4];
        }
        #pragma unroll
        for (int i = 0; i < 4; ++i) {
            int f4 = tid + i * 256;
            int rr = f4 >> 4, kq = (f4 & 15) * 4;
            int row = row0 + rr;
            if (row >= N_NODES) row = N_NODES - 1;
            float4 v = *(const float4*)&x[(size_t)row * IN_FEAT + k0 + kq];
            xt[kq + 0][rr] = v.x; xt[kq + 1][rr] = v.y;
            xt[kq + 2][rr] = v.z; xt[kq + 3][rr] = v.w;
        }
        __syncthreads();

        #pragma unroll 16
        for (int kk = 0; kk < 64; ++kk) {
            float4 a = *(const float4*)&xt[kk][rgrp4];
            float4 b = *(const float4*)&Ws[kk][cgrp4];
            acc[0][0] += a.x * b.x; acc[0][1] += a.x * b.y; acc[0][2] += a.x * b.z; acc[0][3] += a.x * b.w;
            acc[1][0] += a.y * b.x; acc[1][1] += a.y * b.y; acc[1][2] += a.y * b.z; acc[1][3] += a.y * b.w;
            acc[2][0] += a.z * b.x; acc[2][1] += a.z * b.y; acc[2][2] += a.z * b.z; acc[2][3] += a.z * b.w;
            acc[3][0] += a.w * b.x; acc[3][1] += a.w * b.y; acc[3][2] += a.w * b.z; acc[3][3] += a.w * b.w;
        }
        __syncthreads();
    }

    #pragma unroll
    for (int r = 0; r < 4; ++r) {
        int row = row0 + rgrp4 + r;
        if (row < N_NODES) {
            float dn = dinv[row];
            float4 o = make_float4(acc[r][0] * dn, acc[r][1] * dn, acc[r][2] * dn, acc[r][3] * dn);
            *(float4*)&hws[(size_t)row * HIDDEN + cgrp4] = o;
        }
    }
}

// ---------------- register-tiled GEMM 2: hws = (relu(agg) @ W2) * dinv[row] ----------------

__global__ __launch_bounds__(256) void gemm2_tiled_k(const float* __restrict__ agg,
                                                     const float* __restrict__ W,
                                                     const float* __restrict__ dinv,
                                                     float* __restrict__ hws) {
    __shared__ float Ws[64][64];
    __shared__ float xt[64][68];
    int tid = threadIdx.x;
    int row0 = blockIdx.x * TM;
    int rgrp4 = (tid >> 4) * 4;
    int cgrp4 = (tid & 15) * 4;

    #pragma unroll
    for (int i = 0; i < 4; ++i) {
        int f4 = tid + i * 256;
        int kk = f4 >> 4, c4 = (f4 & 15) * 4;
        *(float4*)&Ws[kk][c4] = *(const float4*)&W[(size_t)kk * HIDDEN + c4];
    }
    #pragma unroll
    for (int i = 0; i < 4; ++i) {
        int f4 = tid + i * 256;
        int rr = f4 >> 4, kq = (f4 & 15) * 4;
        int row = row0 + rr;
        if (row >= N_NODES) row = N_NODES - 1;
        float4 v = *(const float4*)&agg[(size_t)row * HIDDEN + kq];
        xt[kq + 0][rr] = fmaxf(v.x, 0.f); xt[kq + 1][rr] = fmaxf(v.y, 0.f);
        xt[kq + 2][rr] = fmaxf(v.z, 0.f); xt[kq + 3][rr] = fmaxf(v.w, 0.f);
    }
    __syncthreads();

    float acc[4][4];
    #pragma unroll
    for (int r = 0; r < 4; ++r)
        #pragma unroll
        for (int c = 0; c < 4; ++c) acc[r][c] = 0.0f;

    #pragma unroll 16
    for (int kk = 0; kk < 64; ++kk) {
        float4 a = *(const float4*)&xt[kk][rgrp4];
        float4 b = *(const float4*)&Ws[kk][cgrp4];
        acc[0][0] += a.x * b.x; acc[0][1] += a.x * b.y; acc[0][2] += a.x * b.z; acc[0][3] += a.x * b.w;
        acc[1][0] += a.y * b.x; acc[1][1] += a.y * b.y; acc[1][2] += a.y * b.z; acc[1][3] += a.y * b.w;
        acc[2][0] += a.z * b.x; acc[2][1] += a.z * b.y; acc[2][2] += a.z * b.z; acc[2][3] += a.z * b.w;
        acc[3][0] += a.w * b.x; acc[3][1] += a.w * b.y; acc[3][2] += a.w * b.z; acc[3][3] += a.w * b.w;
    }

    #pragma unroll
    for (int r = 0; r < 4; ++r) {
        int row = row0 + rgrp4 + r;
        if (row < N_NODES) {
            float dn = dinv[row];
            float4 o = make_float4(acc[r][0] * dn, acc[r][1] * dn, acc[r][2] * dn, acc[r][3] * dn);
            *(float4*)&hws[(size_t)row * HIDDEN + cgrp4] = o;
        }
    }
}

// ---------------- CSR pull: agg[d] = b + dinv[d]*(hws[d] + sum_in hws[s]) ----------------

__global__ __launch_bounds__(256) void pull_k(const int* __restrict__ row_ptr,
                                              const int* __restrict__ csr_src,
                                              const float* __restrict__ dinv,
                                              const float4* __restrict__ hws4,
                                              const float4* __restrict__ b4,
                                              float4* __restrict__ agg4) {
    int node = (blockIdx.x * 256 + threadIdx.x) >> 6;
    int lane = threadIdx.x & 63;
    int g = lane >> 4;
    int fl = lane & 15;
    if (node >= N_NODES) return;

    int start = row_ptr[node];
    int end = row_ptr[node + 1];

    float4 acc = make_float4(0.f, 0.f, 0.f, 0.f);
    if (g == 0) acc = hws4[(size_t)node * 16 + fl];

    for (int i = start; i < end; i += 4) {
        int e = i + g;
        if (e < end) {
            int s = csr_src[e];
            float4 v = hws4[(size_t)s * 16 + fl];
            acc.x += v.x; acc.y += v.y; acc.z += v.z; acc.w += v.w;
        }
    }

    #pragma unroll
    for (int m = 16; m <= 32; m <<= 1) {
        acc.x += __shfl_xor(acc.x, m, 64);
        acc.y += __shfl_xor(acc.y, m, 64);
        acc.z += __shfl_xor(acc.z, m, 64);
        acc.w += __shfl_xor(acc.w, m, 64);
    }

    if (g == 0) {
        float dn = dinv[node];
        float4 bb = b4[fl];
        float4 o;
        o.x = bb.x + dn * acc.x;
        o.y = bb.y + dn * acc.y;
        o.z = bb.z + dn * acc.z;
        o.w = bb.w + dn * acc.w;
        agg4[(size_t)node * 16 + fl] = o;
    }
}

// ---------------- final: out = relu(agg) @ Wl + bl ----------------

__global__ __launch_bounds__(256) void final_k(const float* __restrict__ agg,
                                               const float* __restrict__ Wl,
                                               const float* __restrict__ bl,
                                               float* __restrict__ out) {
    __shared__ float Ws[HIDDEN * N_CLASSES];
    __shared__ float hs[16][HIDDEN + 1];
    int tid = threadIdx.x;

    if (tid < HIDDEN * N_CLASSES / 4) ((float4*)Ws)[tid] = ((const float4*)Wl)[tid];

    int row0 = blockIdx.x * 16;
    for (int i = tid; i < 16 * HIDDEN; i += 256) {
        int rr = i >> 6;
        int kk = i & 63;
        hs[rr][kk] = fmaxf(agg[(size_t)(row0 + rr) * HIDDEN + kk], 0.0f);
    }
    __syncthreads();

    int col = tid & 15;
    int r = tid >> 4;
    float acc = bl[col];
    #pragma unroll
    for (int k = 0; k < HIDDEN; ++k)
        acc += hs[r][k] * Ws[k * N_CLASSES + col];
    out[(size_t)(row0 + r) * N_CLASSES + col] = acc;
}

// ---------------- launch ----------------

extern "C" void kernel_launch(void* const* d_in, const int* in_sizes, int n_in,
                              void* d_out, int out_size, void* d_ws, size_t ws_size,
                              hipStream_t stream) {
    const float* x  = (const float*)d_in[0];
    const int*   ei = (const int*)d_in[1];
    const float* W1 = (const float*)d_in[2];
    const float* b1 = (const float*)d_in[3];
    const float* W2 = (const float*)d_in[4];
    const float* b2 = (const float*)d_in[5];
    const float* Wl = (const float*)d_in[6];
    const float* bl = (const float*)d_in[7];
    float* out = (float*)d_out;

    const int* src = ei;
    const int* dst = ei + N_EDGES;

    float* hws     = (float*)d_ws;                            // N*64
    float* agg     = hws + (size_t)N_NODES * HIDDEN;          // N*64
    int2*  pairs   = (int2*)agg;                              // E pairs (12.8MB) alias agg: dead before pull writes agg
    int*   csr_src = (int*)(agg + (size_t)N_NODES * HIDDEN);  // E
    int*   deg     = csr_src + N_EDGES;                       // N
    float* dinv    = (float*)(deg + N_NODES);                 // N
    int*   row_ptr = (int*)(dinv + N_NODES);                  // N+4
    int*   blk_sum = row_ptr + N_NODES + 4;                   // 200
    int*   blk_off = blk_sum + 200;                           // 200
    int*   bcur    = blk_off + 200;                           // 200

    // --- degree + row_ptr ---
    zero_deg_k<<<(N_NODES + 255) / 256, 256, 0, stream>>>(deg);
    hist_sliced_k<<<NCHUNK * NSLICE, 256, 0, stream>>>(dst, deg);
    dinv_k<<<(N_NODES + 255) / 256, 256, 0, stream>>>(deg, dinv);
    chunk_sum_k<<<NB, 256, 0, stream>>>(deg, blk_sum);
    scan_blocks_k<<<1, 256, 0, stream>>>(blk_sum, blk_off, row_ptr);
    rowptr_k<<<NB, 256, 0, stream>>>(deg, blk_off, row_ptr);
    bcur_init_k<<<1, 256, 0, stream>>>(row_ptr, bcur);

    // --- CSR fill: coarse bucket partition + per-bucket fine placement ---
    coarse_k<<<NCB, 256, 0, stream>>>(src, dst, bcur, pairs);
    fine_k<<<NBUK, 256, 0, stream>>>(pairs, row_ptr, csr_src);

    // --- layer 1 ---
    gemm1_tiled_k<<<GBLK, 256, 0, stream>>>(x, W1, dinv, hws);
    pull_k<<<(N_NODES * 64 + 255) / 256, 256, 0, stream>>>(row_ptr, csr_src, dinv,
                                                           (const float4*)hws,
                                                           (const float4*)b1,
                                                           (float4*)agg);

    // --- layer 2 ---
    gemm2_tiled_k<<<GBLK, 256, 0, stream>>>(agg, W2, dinv, hws);
    pull_k<<<(N_NODES * 64 + 255) / 256, 256, 0, stream>>>(row_ptr, csr_src, dinv,
                                                           (const float4*)hws,
                                                           (const float4*)b2,
                                                           (float4*)agg);

    // --- classifier head ---
    final_k<<<N_NODES / 16, 256, 0, stream>>>(agg, Wl, bl, out);
}